// Round 7
// baseline (204.500 us; speedup 1.0000x reference)
//
#include <hip/hip_runtime.h>
#include <hip/hip_bf16.h>
#include <cstdint>
#include <cstddef>

#define NB 4
#define CIN 256
#define CHID 128
#define HEADS 4
#define CHEAD 32
#define NPOS 4096      // 64*64
#define BH 16          // NB*HEADS
#define NTOT 16384     // NB*NPOS
#define QKV_O 384
// 32^-0.5 * log2(e): Q pre-scaled so softmax logits feed exp2 directly
#define QSCALE_LOG2E 0.2550348229f

typedef float f32x4 __attribute__((ext_vector_type(4)));
typedef float f32x16 __attribute__((ext_vector_type(16)));
typedef short s16x8 __attribute__((ext_vector_type(8)));

static __device__ __forceinline__ unsigned short f2bf(float f) {
    union { float f; unsigned u; } v; v.f = f;
    unsigned r = v.u + 0x7FFFu + ((v.u >> 16) & 1u);
    return (unsigned short)(r >> 16);
}

static __device__ __forceinline__ unsigned int pk2bf(float a, float b) {
    union { __hip_bfloat162 h; unsigned int u; } c;
    c.h = __float22bfloat162_rn(float2{a, b});
    return c.u;
}

// Exchange upper-half lanes of a with lower-half lanes of b (gfx950 VALU op).
static __device__ __forceinline__ void plswap(unsigned& a, unsigned& b) {
#if __has_builtin(__builtin_amdgcn_permlane32_swap)
    auto r = __builtin_amdgcn_permlane32_swap((int)a, (int)b, false, false);
    a = (unsigned)r[0];
    b = (unsigned)r[1];
#else
    int hh = (threadIdx.x >> 5) & 1;
    unsigned ta = (unsigned)__shfl_xor((int)a, 32);
    unsigned tb = (unsigned)__shfl_xor((int)b, 32);
    unsigned na = hh ? tb : a;
    unsigned nb = hh ? b : ta;
    a = na; b = nb;
#endif
}

static __device__ __forceinline__ s16x8 mk8(unsigned a, unsigned b, unsigned c, unsigned d) {
    union { unsigned u[4]; s16x8 v; } x;
    x.u[0] = a; x.u[1] = b; x.u[2] = c; x.u[3] = d;
    return x.v;
}

static __device__ __forceinline__ void async_cp16(const void* g, void* l) {
    __builtin_amdgcn_global_load_lds((const __attribute__((address_space(1))) unsigned int*)g,
                                     (__attribute__((address_space(3))) unsigned int*)l, 16, 0, 0);
}

#define MFMA32(a, b, c) __builtin_amdgcn_mfma_f32_32x32x16_bf16(a, b, c, 0, 0, 0)

// ---------------- kernel 1: transpose x -> xT bf16, fused weight convert ----------------
#define TBLOCKS (NB * (CIN / 32) * (NPOS / 32))   // 4096
__global__ __launch_bounds__(256) void k_prep(const float* __restrict__ x,
                                              unsigned short* __restrict__ xT,
                                              const float* __restrict__ wqkv,
                                              const float* __restrict__ wout,
                                              unsigned short* __restrict__ wqkv_bf,
                                              unsigned short* __restrict__ wout_bf) {
    if (blockIdx.x >= TBLOCKS) {   // weight-convert tail blocks
        int i = (blockIdx.x - TBLOCKS) * 256 + threadIdx.x;
        if (i < QKV_O * CIN) wqkv_bf[i] = f2bf(wqkv[i]);
        if (i < CIN * CHID)  wout_bf[i] = f2bf(wout[i]);
        return;
    }
    __shared__ float tile[32][33];
    const int ntiles = NPOS / 32;   // 128
    const int ctiles = CIN / 32;    // 8
    int b   = blockIdx.x / (ntiles * ctiles);
    int rem = blockIdx.x % (ntiles * ctiles);
    int ct = rem / ntiles;
    int nt = rem % ntiles;
    int c0 = ct * 32, n0 = nt * 32;
    int tc = threadIdx.x / 32;
    int tn = threadIdx.x % 32;
    const float* xb = x + (size_t)b * CIN * NPOS;
#pragma unroll
    for (int it = 0; it < 4; ++it) {
        int c = tc + it * 8;
        tile[c][tn] = xb[(size_t)(c0 + c) * NPOS + n0 + tn];
    }
    __syncthreads();
    unsigned short* xTb = xT + (size_t)b * NPOS * CIN;
#pragma unroll
    for (int it = 0; it < 4; ++it) {
        int n = tc + it * 8;
        xTb[(size_t)(n0 + n) * CIN + c0 + tn] = f2bf(tile[tn][n]);
    }
}

// ---------------- kernel 2: QKV projection GEMM, LDS-staged ----------------
// mt==0 -> pure Q, mt==1 -> pure K, mt==2 -> pure V (LDS-transposed epilogue)
__global__ __launch_bounds__(256, 4) void k_qkv(const unsigned short* __restrict__ wq,
                                                const unsigned short* __restrict__ xT,
                                                unsigned short* __restrict__ Q,
                                                unsigned short* __restrict__ K,
                                                unsigned short* __restrict__ V) {
    __shared__ __align__(16) unsigned char smem[2 * 12288];   // 24 KB
    int mt = blockIdx.x % 3;
    int nt = blockIdx.x / 3;
    int wid = threadIdx.x >> 6, lane = threadIdx.x & 63;
    int quad = lane >> 4, low4 = lane & 15;
    int o0 = mt * 128, n0 = nt * 64;
    int lb = lane * 16;

    const unsigned short* srcA0 = wq + (size_t)(o0 + wid * 32 + low4) * CIN + quad * 8;
    const unsigned short* srcA1 = srcA0 + 16 * CIN;
    const unsigned short* srcB  = xT + (size_t)(n0 + wid * 16 + low4) * CIN + quad * 8;
    int dA0 = wid * 2048, dA1 = dA0 + 1024, dB = 8192 + wid * 1024;

    async_cp16(srcA0, smem + dA0 + lb);
    async_cp16(srcA1, smem + dA1 + lb);
    async_cp16(srcB,  smem + dB  + lb);
    __syncthreads();

    f32x4 acc[2][4] = {};
    for (int c = 0; c < 8; ++c) {
        if (c < 7) {
            unsigned char* nxt = smem + ((c + 1) & 1) * 12288;
            async_cp16(srcA0 + (c + 1) * 32, nxt + dA0 + lb);
            async_cp16(srcA1 + (c + 1) * 32, nxt + dA1 + lb);
            async_cp16(srcB  + (c + 1) * 32, nxt + dB  + lb);
        }
        const unsigned char* cur = smem + (c & 1) * 12288;
        s16x8 a0 = *(const s16x8*)(cur + wid * 2048 + lb);
        s16x8 a1 = *(const s16x8*)(cur + wid * 2048 + 1024 + lb);
#pragma unroll
        for (int j = 0; j < 4; ++j) {
            s16x8 bj = *(const s16x8*)(cur + 8192 + j * 1024 + lb);
            acc[0][j] = __builtin_amdgcn_mfma_f32_16x16x32_bf16(a0, bj, acc[0][j], 0, 0, 0);
            acc[1][j] = __builtin_amdgcn_mfma_f32_16x16x32_bf16(a1, bj, acc[1][j], 0, 0, 0);
        }
        __syncthreads();
    }

    if (mt < 2) {
        unsigned short* dst = (mt == 0) ? Q : K;
        float sc = (mt == 0) ? QSCALE_LOG2E : 1.0f;
#pragma unroll
        for (int i = 0; i < 2; ++i) {
            int ol = wid * 32 + i * 16 + quad * 4;
            int head = ol >> 5, ch = ol & 31;
#pragma unroll
            for (int j = 0; j < 4; ++j) {
                int nG = n0 + j * 16 + low4;
                int b = nG >> 12, n = nG & 4095;
                f32x4 v = acc[i][j];
                unsigned long long d =
                    (unsigned long long)pk2bf(v[0] * sc, v[1] * sc) |
                    ((unsigned long long)pk2bf(v[2] * sc, v[3] * sc) << 32);
                *(unsigned long long*)(dst + ((size_t)(b * 4 + head) * NPOS + n) * 32 + ch) = d;
            }
        }
    } else {
        // V: transpose 128(ch) x 64(n) through LDS, store V^T coalesced b128
        unsigned short* vt = (unsigned short*)smem;   // [128][80] shorts (20 KB), rows 16B-aligned
#pragma unroll
        for (int i = 0; i < 2; ++i) {
            int ol = wid * 32 + i * 16 + quad * 4;
#pragma unroll
            for (int j = 0; j < 4; ++j) {
                int col = j * 16 + low4;
#pragma unroll
                for (int r = 0; r < 4; ++r) vt[(ol + r) * 80 + col] = f2bf(acc[i][j][r]);
            }
        }
        __syncthreads();
        int b = n0 >> 12, nbase = n0 & 4095;
#pragma unroll
        for (int rep = 0; rep < 4; ++rep) {
            int idx = rep * 256 + threadIdx.x;
            int row = idx >> 3, c8 = idx & 7;
            s16x8 val = *(const s16x8*)(vt + row * 80 + c8 * 8);
            int head = row >> 5, ch = row & 31;
            *(s16x8*)(V + ((size_t)((b * 4 + head) * 32 + ch)) * NPOS + nbase + c8 * 8) = val;
        }
    }
}

// ---------------- kernel 3: attention, 512-thread blocks, split-K x4 ----------------
// Grid: qt(32) x bh(16), blockIdx = qt*16 + bh. Block: 8 waves = qg(2) x kh(4).
// Wave: 64 queries (qg), 1024 keys (kh), 16 iters of 64 keys. Per kh: K 4KB + V 4KB
// staged into dbuf LDS (frag order) by its wave pair. 32x32x16 MFMA; permlane P
// transform (no P LDS round-trip). 4-way key-half combine through LDS at the end.
__global__ __launch_bounds__(512, 4) void k_attn(const unsigned short* __restrict__ Q,
                                                 const unsigned short* __restrict__ K,
                                                 const unsigned short* __restrict__ V,
                                                 unsigned short* __restrict__ attnO) {
    __shared__ __align__(16) unsigned char smem[65536];   // 2 x 32 KB dbuf; combine reuses
    int bh = blockIdx.x & 15;
    int qt = blockIdx.x >> 4;          // 0..31
    int wid = threadIdx.x >> 6;        // 0..7
    int lane = threadIdx.x & 63;
    int q5 = lane & 31, h = lane >> 5;
    int qg = wid & 1, kh = wid >> 1;   // kh 0..3
    int q0 = qt * 128 + qg * 64;
    int khk = kh * 1024;

    const unsigned short* Qp  = Q + (size_t)bh * NPOS * 32;
    const unsigned short* Kbh = K + (size_t)bh * NPOS * 32;
    const unsigned short* Vbh = V + (size_t)bh * 32 * NPOS;

    // Q B-frags [n-tile][ch-chunk]
    s16x8 bq00 = *(const s16x8*)(Qp + (size_t)(q0 + q5) * 32 + h * 8);
    s16x8 bq01 = *(const s16x8*)(Qp + (size_t)(q0 + q5) * 32 + 16 + h * 8);
    s16x8 bq10 = *(const s16x8*)(Qp + (size_t)(q0 + 32 + q5) * 32 + h * 8);
    s16x8 bq11 = *(const s16x8*)(Qp + (size_t)(q0 + 32 + q5) * 32 + 16 + h * 8);

    const unsigned short* sK = Kbh + (size_t)q5 * 32 + h * 8;
    const unsigned short* sV = Vbh + (size_t)q5 * NPOS + h * 8;

    auto stage = [&](int bufi, int k0) {
        unsigned char* wb = smem + bufi * 32768 + kh * 8192;
        if (qg == 0) {   // K: tiles t=0,1 x frags f=0,1
            const unsigned short* p = sK + (size_t)k0 * 32;
            async_cp16(p,        wb);
            async_cp16(p + 16,   wb + 1024);
            async_cp16(p + 1024, wb + 2048);
            async_cp16(p + 1040, wb + 3072);
        } else {         // V: 16-key chunks c=0..3
            const unsigned short* p = sV + k0;
            async_cp16(p,      wb + 4096);
            async_cp16(p + 16, wb + 5120);
            async_cp16(p + 32, wb + 6144);
            async_cp16(p + 48, wb + 7168);
        }
    };

    f32x16 oT0 = {}, oT1 = {};
    float l0a = 0.0f, l0b = 0.0f, l1a = 0.0f, l1b = 0.0f;   // tree-split lsum accumulators
    const int lby = lane * 16;

    stage(0, khk);
    __syncthreads();

#pragma unroll 1
    for (int it = 0; it < 16; ++it) {
        if (it + 1 < 16) stage((it + 1) & 1, khk + (it + 1) * 64);
        const unsigned char* kb = smem + (it & 1) * 32768 + kh * 8192;
#pragma unroll
        for (int t = 0; t < 2; ++t) {
            s16x8 ak0 = *(const s16x8*)(kb + t * 2048 + lby);
            s16x8 ak1 = *(const s16x8*)(kb + t * 2048 + 1024 + lby);
            f32x16 s0 = {}, s1 = {};
            s0 = MFMA32(ak0, bq00, s0); s0 = MFMA32(ak1, bq01, s0);
            s1 = MFMA32(ak0, bq10, s1); s1 = MFMA32(ak1, bq11, s1);
            unsigned p0[8], p1[8];
#pragma unroll
            for (int i = 0; i < 8; ++i) {
                float a0 = __builtin_amdgcn_exp2f(s0[2 * i]);
                float a1 = __builtin_amdgcn_exp2f(s0[2 * i + 1]);
                float b0 = __builtin_amdgcn_exp2f(s1[2 * i]);
                float b1 = __builtin_amdgcn_exp2f(s1[2 * i + 1]);
                if (i & 1) { l0a += a0 + a1; l1a += b0 + b1; }
                else       { l0b += a0 + a1; l1b += b0 + b1; }
                p0[i] = pk2bf(a0, a1);
                p1[i] = pk2bf(b0, b1);
            }
            plswap(p0[0], p0[2]); plswap(p0[1], p0[3]);
            plswap(p0[4], p0[6]); plswap(p0[5], p0[7]);
            plswap(p1[0], p1[2]); plswap(p1[1], p1[3]);
            plswap(p1[4], p1[6]); plswap(p1[5], p1[7]);
            s16x8 bp0lo = mk8(p0[0], p0[1], p0[2], p0[3]);
            s16x8 bp0hi = mk8(p0[4], p0[5], p0[6], p0[7]);
            s16x8 bp1lo = mk8(p1[0], p1[1], p1[2], p1[3]);
            s16x8 bp1hi = mk8(p1[4], p1[5], p1[6], p1[7]);

            s16x8 av0 = *(const s16x8*)(kb + 4096 + (2 * t) * 1024 + lby);
            s16x8 av1 = *(const s16x8*)(kb + 4096 + (2 * t + 1) * 1024 + lby);
            oT0 = MFMA32(av0, bp0lo, oT0); oT0 = MFMA32(av1, bp0hi, oT0);
            oT1 = MFMA32(av0, bp1lo, oT1); oT1 = MFMA32(av1, bp1hi, oT1);
        }
        __syncthreads();
    }

    float lsum0 = l0a + l0b, lsum1 = l1a + l1b;
    lsum0 += __shfl_xor(lsum0, 32);
    lsum1 += __shfl_xor(lsum1, 32);

    // 4-way combine through LDS: kh=1..3 dump; kh=0 accumulates + stores
    // slot layout: 2176 floats (8704 B) per (kh-1, qg): 1024 oT0 + 1024 oT1 + 128 lsum
    if (kh) {
        float* area = (float*)(smem + ((kh - 1) * 2 + qg) * 8704);
#pragma unroll
        for (int j = 0; j < 4; ++j) {
            *(f32x4*)(area + j * 256 + lane * 4) =
                f32x4{oT0[4 * j], oT0[4 * j + 1], oT0[4 * j + 2], oT0[4 * j + 3]};
            *(f32x4*)(area + 1024 + j * 256 + lane * 4) =
                f32x4{oT1[4 * j], oT1[4 * j + 1], oT1[4 * j + 2], oT1[4 * j + 3]};
        }
        area[2048 + lane * 2]     = lsum0;
        area[2048 + lane * 2 + 1] = lsum1;
    }
    __syncthreads();
    if (!kh) {
#pragma unroll
        for (int m = 0; m < 3; ++m) {
            const float* area = (const float*)(smem + (m * 2 + qg) * 8704);
#pragma unroll
            for (int j = 0; j < 4; ++j) {
                f32x4 r0 = *(const f32x4*)(area + j * 256 + lane * 4);
                f32x4 r1 = *(const f32x4*)(area + 1024 + j * 256 + lane * 4);
#pragma unroll
                for (int i = 0; i < 4; ++i) {
                    oT0[4 * j + i] += r0[i];
                    oT1[4 * j + i] += r1[i];
                }
            }
            lsum0 += area[2048 + lane * 2];
            lsum1 += area[2048 + lane * 2 + 1];
        }
        float inv0 = 1.0f / lsum0, inv1 = 1.0f / lsum1;
        int b = bh >> 2, head = bh & 3;
        int n0q = q0 + q5, n1q = q0 + 32 + q5;
        unsigned short* base0 = attnO + ((size_t)(b * NPOS + n0q)) * CHID + head * 32 + 4 * h;
        unsigned short* base1 = attnO + ((size_t)(b * NPOS + n1q)) * CHID + head * 32 + 4 * h;
#pragma unroll
        for (int j = 0; j < 4; ++j) {
            unsigned long long d0 =
                (unsigned long long)pk2bf(oT0[4 * j] * inv0, oT0[4 * j + 1] * inv0) |
                ((unsigned long long)pk2bf(oT0[4 * j + 2] * inv0, oT0[4 * j + 3] * inv0) << 32);
            *(unsigned long long*)(base0 + 8 * j) = d0;
            unsigned long long d1 =
                (unsigned long long)pk2bf(oT1[4 * j] * inv1, oT1[4 * j + 1] * inv1) |
                ((unsigned long long)pk2bf(oT1[4 * j + 2] * inv1, oT1[4 * j + 3] * inv1) << 32);
            *(unsigned long long*)(base1 + 8 * j) = d1;
        }
    }
}

// ---------------- kernel 4: output projection GEMM + bias, LDS-staged ----------------
__global__ __launch_bounds__(256, 4) void k_out(const unsigned short* __restrict__ wo,
                                                const unsigned short* __restrict__ attnO,
                                                const float* __restrict__ bias,
                                                float* __restrict__ out) {
    __shared__ __align__(16) unsigned char smem[2 * 12288];   // 24 KB
    int mt = blockIdx.x & 1;
    int nt = blockIdx.x >> 1;
    int wid = threadIdx.x >> 6, lane = threadIdx.x & 63;
    int quad = lane >> 4, low4 = lane & 15;
    int o0 = mt * 128, n0 = nt * 64;
    int lb = lane * 16;

    const unsigned short* srcA0 = wo + (size_t)(o0 + wid * 32 + low4) * CHID + quad * 8;
    const unsigned short* srcA1 = srcA0 + 16 * CHID;
    const unsigned short* srcB  = attnO + (size_t)(n0 + wid * 16 + low4) * CHID + quad * 8;
    int dA0 = wid * 2048, dA1 = dA0 + 1024, dB = 8192 + wid * 1024;

    async_cp16(srcA0, smem + dA0 + lb);
    async_cp16(srcA1, smem + dA1 + lb);
    async_cp16(srcB,  smem + dB  + lb);
    __syncthreads();

    f32x4 acc[2][4] = {};
    for (int c = 0; c < 4; ++c) {
        if (c < 3) {
            unsigned char* nxt = smem + ((c + 1) & 1) * 12288;
            async_cp16(srcA0 + (c + 1) * 32, nxt + dA0 + lb);
            async_cp16(srcA1 + (c + 1) * 32, nxt + dA1 + lb);
            async_cp16(srcB  + (c + 1) * 32, nxt + dB  + lb);
        }
        const unsigned char* cur = smem + (c & 1) * 12288;
        s16x8 a0 = *(const s16x8*)(cur + wid * 2048 + lb);
        s16x8 a1 = *(const s16x8*)(cur + wid * 2048 + 1024 + lb);
#pragma unroll
        for (int j = 0; j < 4; ++j) {
            s16x8 bj = *(const s16x8*)(cur + 8192 + j * 1024 + lb);
            acc[0][j] = __builtin_amdgcn_mfma_f32_16x16x32_bf16(a0, bj, acc[0][j], 0, 0, 0);
            acc[1][j] = __builtin_amdgcn_mfma_f32_16x16x32_bf16(a1, bj, acc[1][j], 0, 0, 0);
        }
        __syncthreads();
    }

#pragma unroll
    for (int i = 0; i < 2; ++i) {
        int ob = o0 + wid * 32 + i * 16 + quad * 4;
#pragma unroll
        for (int j = 0; j < 4; ++j) {
            int nG = n0 + j * 16 + low4;
            int b = nG >> 12, n = nG & 4095;
#pragma unroll
            for (int r = 0; r < 4; ++r) {
                int o = ob + r;
                out[((size_t)(b * CIN + o)) * NPOS + n] = acc[i][j][r] + bias[o];
            }
        }
    }
}

extern "C" void kernel_launch(void* const* d_in, const int* in_sizes, int n_in,
                              void* d_out, int out_size, void* d_ws, size_t ws_size,
                              hipStream_t stream) {
    const float* x    = (const float*)d_in[0];
    const float* wqkv = (const float*)d_in[1];
    const float* wout = (const float*)d_in[2];
    const float* bout = (const float*)d_in[3];
    float* out = (float*)d_out;

    unsigned short* Q       = (unsigned short*)d_ws;
    unsigned short* K       = Q + (size_t)BH * NPOS * 32;       // +4 MB
    unsigned short* V       = K + (size_t)BH * NPOS * 32;       // +4 MB
    unsigned short* attnO   = V + (size_t)BH * 32 * NPOS;       // +4 MB
    unsigned short* xT      = attnO + (size_t)NTOT * CHID;      // +4 MB
    unsigned short* wqkv_bf = xT + (size_t)NTOT * CIN;          // +8 MB
    unsigned short* wout_bf = wqkv_bf + QKV_O * CIN;            // +192 KB

    k_prep<<<TBLOCKS + (QKV_O * CIN + 255) / 256, 256, 0, stream>>>(x, xT, wqkv, wout, wqkv_bf, wout_bf);
    k_qkv<<<3 * (NTOT / 64), 256, 0, stream>>>(wqkv_bf, xT, Q, K, V);
    k_attn<<<(NPOS / 128) * BH, 512, 0, stream>>>(Q, K, V, attnO);
    k_out<<<2 * (NTOT / 64), 256, 0, stream>>>(wout_bf, attnO, bout, out);
}

// Round 10
// 151.274 us; speedup vs baseline: 1.3519x; 1.3519x over previous
//
#include <hip/hip_runtime.h>
#include <hip/hip_bf16.h>
#include <cstdint>
#include <cstddef>

// Round 10 build (R8 design, cache-busting resubmission #3)

#define NB 4
#define CIN 256
#define CHID 128
#define HEADS 4
#define CHEAD 32
#define NPOS 4096      // 64*64
#define BH 16          // NB*HEADS
#define NTOT 16384     // NB*NPOS
#define QKV_O 384
// 32^-0.5 * log2(e): Q pre-scaled so softmax logits feed exp2 directly
#define QSCALE_LOG2E 0.2550348229f

typedef float f32x4 __attribute__((ext_vector_type(4)));
typedef float f32x16 __attribute__((ext_vector_type(16)));
typedef short s16x8 __attribute__((ext_vector_type(8)));

static __device__ __forceinline__ unsigned short f2bf(float f) {
    union { float f; unsigned u; } v; v.f = f;
    unsigned r = v.u + 0x7FFFu + ((v.u >> 16) & 1u);
    return (unsigned short)(r >> 16);
}

static __device__ __forceinline__ unsigned int pk2bf(float a, float b) {
    union { __hip_bfloat162 h; unsigned int u; } c;
    c.h = __float22bfloat162_rn(float2{a, b});
    return c.u;
}

// Exchange upper-half lanes of a with lower-half lanes of b (gfx950 VALU op).
static __device__ __forceinline__ void plswap(unsigned& a, unsigned& b) {
#if __has_builtin(__builtin_amdgcn_permlane32_swap)
    auto r = __builtin_amdgcn_permlane32_swap((int)a, (int)b, false, false);
    a = (unsigned)r[0];
    b = (unsigned)r[1];
#else
    int hh = (threadIdx.x >> 5) & 1;
    unsigned ta = (unsigned)__shfl_xor((int)a, 32);
    unsigned tb = (unsigned)__shfl_xor((int)b, 32);
    unsigned na = hh ? tb : a;
    unsigned nb = hh ? b : ta;
    a = na; b = nb;
#endif
}

static __device__ __forceinline__ s16x8 mk8(unsigned a, unsigned b, unsigned c, unsigned d) {
    union { unsigned u[4]; s16x8 v; } x;
    x.u[0] = a; x.u[1] = b; x.u[2] = c; x.u[3] = d;
    return x.v;
}

static __device__ __forceinline__ void async_cp16(const void* g, void* l) {
    __builtin_amdgcn_global_load_lds((const __attribute__((address_space(1))) unsigned int*)g,
                                     (__attribute__((address_space(3))) unsigned int*)l, 16, 0, 0);
}

#define MFMA32(a, b, c) __builtin_amdgcn_mfma_f32_32x32x16_bf16(a, b, c, 0, 0, 0)

// ---------------- kernel 1: transpose x -> xT bf16, fused weight convert ----------------
#define TBLOCKS (NB * (CIN / 32) * (NPOS / 32))   // 4096
__global__ __launch_bounds__(256) void k_prep(const float* __restrict__ x,
                                              unsigned short* __restrict__ xT,
                                              const float* __restrict__ wqkv,
                                              const float* __restrict__ wout,
                                              unsigned short* __restrict__ wqkv_bf,
                                              unsigned short* __restrict__ wout_bf) {
    if (blockIdx.x >= TBLOCKS) {   // weight-convert tail blocks
        int i = (blockIdx.x - TBLOCKS) * 256 + threadIdx.x;
        if (i < QKV_O * CIN) wqkv_bf[i] = f2bf(wqkv[i]);
        if (i < CIN * CHID)  wout_bf[i] = f2bf(wout[i]);
        return;
    }
    __shared__ float tile[32][33];
    const int ntiles = NPOS / 32;   // 128
    const int ctiles = CIN / 32;    // 8
    int b   = blockIdx.x / (ntiles * ctiles);
    int rem = blockIdx.x % (ntiles * ctiles);
    int ct = rem / ntiles;
    int nt = rem % ntiles;
    int c0 = ct * 32, n0 = nt * 32;
    int tc = threadIdx.x / 32;
    int tn = threadIdx.x % 32;
    const float* xb = x + (size_t)b * CIN * NPOS;
#pragma unroll
    for (int it = 0; it < 4; ++it) {
        int c = tc + it * 8;
        tile[c][tn] = xb[(size_t)(c0 + c) * NPOS + n0 + tn];
    }
    __syncthreads();
    unsigned short* xTb = xT + (size_t)b * NPOS * CIN;
#pragma unroll
    for (int it = 0; it < 4; ++it) {
        int n = tc + it * 8;
        xTb[(size_t)(n0 + n) * CIN + c0 + tn] = f2bf(tile[tn][n]);
    }
}

// ---------------- kernel 2: QKV projection GEMM, LDS-staged ----------------
// mt==0 -> pure Q, mt==1 -> pure K, mt==2 -> pure V (LDS-transposed epilogue)
__global__ __launch_bounds__(256, 4) void k_qkv(const unsigned short* __restrict__ wq,
                                                const unsigned short* __restrict__ xT,
                                                unsigned short* __restrict__ Q,
                                                unsigned short* __restrict__ K,
                                                unsigned short* __restrict__ V) {
    __shared__ __align__(16) unsigned char smem[2 * 12288];   // 24 KB
    int mt = blockIdx.x % 3;
    int nt = blockIdx.x / 3;
    int wid = threadIdx.x >> 6, lane = threadIdx.x & 63;
    int quad = lane >> 4, low4 = lane & 15;
    int o0 = mt * 128, n0 = nt * 64;
    int lb = lane * 16;

    const unsigned short* srcA0 = wq + (size_t)(o0 + wid * 32 + low4) * CIN + quad * 8;
    const unsigned short* srcA1 = srcA0 + 16 * CIN;
    const unsigned short* srcB  = xT + (size_t)(n0 + wid * 16 + low4) * CIN + quad * 8;
    int dA0 = wid * 2048, dA1 = dA0 + 1024, dB = 8192 + wid * 1024;

    async_cp16(srcA0, smem + dA0 + lb);
    async_cp16(srcA1, smem + dA1 + lb);
    async_cp16(srcB,  smem + dB  + lb);
    __syncthreads();

    f32x4 acc[2][4] = {};
    for (int c = 0; c < 8; ++c) {
        if (c < 7) {
            unsigned char* nxt = smem + ((c + 1) & 1) * 12288;
            async_cp16(srcA0 + (c + 1) * 32, nxt + dA0 + lb);
            async_cp16(srcA1 + (c + 1) * 32, nxt + dA1 + lb);
            async_cp16(srcB  + (c + 1) * 32, nxt + dB  + lb);
        }
        const unsigned char* cur = smem + (c & 1) * 12288;
        s16x8 a0 = *(const s16x8*)(cur + wid * 2048 + lb);
        s16x8 a1 = *(const s16x8*)(cur + wid * 2048 + 1024 + lb);
#pragma unroll
        for (int j = 0; j < 4; ++j) {
            s16x8 bj = *(const s16x8*)(cur + 8192 + j * 1024 + lb);
            acc[0][j] = __builtin_amdgcn_mfma_f32_16x16x32_bf16(a0, bj, acc[0][j], 0, 0, 0);
            acc[1][j] = __builtin_amdgcn_mfma_f32_16x16x32_bf16(a1, bj, acc[1][j], 0, 0, 0);
        }
        __syncthreads();
    }

    if (mt < 2) {
        unsigned short* dst = (mt == 0) ? Q : K;
        float sc = (mt == 0) ? QSCALE_LOG2E : 1.0f;
#pragma unroll
        for (int i = 0; i < 2; ++i) {
            int ol = wid * 32 + i * 16 + quad * 4;
            int head = ol >> 5, ch = ol & 31;
#pragma unroll
            for (int j = 0; j < 4; ++j) {
                int nG = n0 + j * 16 + low4;
                int b = nG >> 12, n = nG & 4095;
                f32x4 v = acc[i][j];
                unsigned long long d =
                    (unsigned long long)pk2bf(v[0] * sc, v[1] * sc) |
                    ((unsigned long long)pk2bf(v[2] * sc, v[3] * sc) << 32);
                *(unsigned long long*)(dst + ((size_t)(b * 4 + head) * NPOS + n) * 32 + ch) = d;
            }
        }
    } else {
        // V: transpose 128(ch) x 64(n) through LDS, store V^T coalesced b128
        unsigned short* vt = (unsigned short*)smem;   // [128][80] shorts (20 KB), rows 16B-aligned
#pragma unroll
        for (int i = 0; i < 2; ++i) {
            int ol = wid * 32 + i * 16 + quad * 4;
#pragma unroll
            for (int j = 0; j < 4; ++j) {
                int col = j * 16 + low4;
#pragma unroll
                for (int r = 0; r < 4; ++r) vt[(ol + r) * 80 + col] = f2bf(acc[i][j][r]);
            }
        }
        __syncthreads();
        int b = n0 >> 12, nbase = n0 & 4095;
#pragma unroll
        for (int rep = 0; rep < 4; ++rep) {
            int idx = rep * 256 + threadIdx.x;
            int row = idx >> 3, c8 = idx & 7;
            s16x8 val = *(const s16x8*)(vt + row * 80 + c8 * 8);
            int head = row >> 5, ch = row & 31;
            *(s16x8*)(V + ((size_t)((b * 4 + head) * 32 + ch)) * NPOS + nbase + c8 * 8) = val;
        }
    }
}

// ---------------- kernel 3: attention, 32 queries/wave, split-K x2, 1024 blocks ----------------
// Grid: qt(64) x bh(16), blockIdx = qt*16 + bh (same-bh blocks share an XCD).
// Block: 4 waves = qg(2, 32 queries each) x kh(2, 2048 keys each); 4 blocks/CU ->
// 16 waves/CU. Per 64-key iter: K 4KB + V 4KB per kh staged into dbuf LDS (frag
// order) by the kh wave pair. 32x32x16 MFMA; permlane P transform (no LDS P
// round-trip). Key-half combine through LDS at the end. Register budget ~80
// (1 acc + 1 S transient + 2 Q frags) -- fits 128 cap with no spill.
__global__ __launch_bounds__(256, 4) void k_attn(const unsigned short* __restrict__ Q,
                                                 const unsigned short* __restrict__ K,
                                                 const unsigned short* __restrict__ V,
                                                 unsigned short* __restrict__ attnO) {
    __shared__ __align__(16) unsigned char smem[2 * 16384];   // 32 KB dbuf; combine reuses buf0
    int bh = blockIdx.x & 15;
    int qt = blockIdx.x >> 4;          // 0..63
    int wid = threadIdx.x >> 6;        // 0..3
    int lane = threadIdx.x & 63;
    int q5 = lane & 31, h = lane >> 5;
    int qg = wid & 1, kh = wid >> 1;
    int q0 = qt * 64 + qg * 32;
    int khk = kh * 2048;

    const unsigned short* Qp  = Q + (size_t)bh * NPOS * 32;
    const unsigned short* Kbh = K + (size_t)bh * NPOS * 32;
    const unsigned short* Vbh = V + (size_t)bh * 32 * NPOS;

    // Q B-frags (n=query q5, k=ch chunks 0..15 / 16..31)
    s16x8 bq0 = *(const s16x8*)(Qp + (size_t)(q0 + q5) * 32 + h * 8);
    s16x8 bq1 = *(const s16x8*)(Qp + (size_t)(q0 + q5) * 32 + 16 + h * 8);

    const unsigned short* sK = Kbh + (size_t)q5 * 32 + h * 8;
    const unsigned short* sV = Vbh + (size_t)q5 * NPOS + h * 8;

    auto stage = [&](int bufi, int k0) {
        unsigned char* wb = smem + bufi * 16384 + kh * 8192;
        if (qg == 0) {   // K: tiles t=0,1 x ch-chunks f=0,1 (1 KB frags, lane*16 order)
            const unsigned short* p = sK + (size_t)k0 * 32;
            async_cp16(p,        wb);
            async_cp16(p + 16,   wb + 1024);
            async_cp16(p + 1024, wb + 2048);
            async_cp16(p + 1040, wb + 3072);
        } else {         // V: 16-key chunks c=0..3
            const unsigned short* p = sV + k0;
            async_cp16(p,      wb + 4096);
            async_cp16(p + 16, wb + 5120);
            async_cp16(p + 32, wb + 6144);
            async_cp16(p + 48, wb + 7168);
        }
    };

    f32x16 oT = {};
    float lacc0 = 0.0f, lacc1 = 0.0f;   // tree-split lsum accumulators
    const int lby = lane * 16;

    stage(0, khk);
    __syncthreads();

#pragma unroll 1
    for (int it = 0; it < 32; ++it) {
        if (it + 1 < 32) stage((it + 1) & 1, khk + (it + 1) * 64);
        const unsigned char* kb = smem + (it & 1) * 16384 + kh * 8192;
#pragma unroll
        for (int t = 0; t < 2; ++t) {
            s16x8 ak0 = *(const s16x8*)(kb + t * 2048 + lby);
            s16x8 ak1 = *(const s16x8*)(kb + t * 2048 + 1024 + lby);
            f32x16 s = {};
            s = MFMA32(ak0, bq0, s);
            s = MFMA32(ak1, bq1, s);
            unsigned p[8];
#pragma unroll
            for (int i = 0; i < 8; ++i) {
                float e0 = __builtin_amdgcn_exp2f(s[2 * i]);
                float e1 = __builtin_amdgcn_exp2f(s[2 * i + 1]);
                if (i & 1) lacc0 += e0 + e1;
                else       lacc1 += e0 + e1;
                p[i] = pk2bf(e0, e1);
            }
            // C-layout -> B-operand fragment transform (pure VALU)
            plswap(p[0], p[2]); plswap(p[1], p[3]);
            plswap(p[4], p[6]); plswap(p[5], p[7]);
            s16x8 bplo = mk8(p[0], p[1], p[2], p[3]);
            s16x8 bphi = mk8(p[4], p[5], p[6], p[7]);

            s16x8 av0 = *(const s16x8*)(kb + 4096 + (2 * t) * 1024 + lby);
            s16x8 av1 = *(const s16x8*)(kb + 4096 + (2 * t + 1) * 1024 + lby);
            oT = MFMA32(av0, bplo, oT);
            oT = MFMA32(av1, bphi, oT);
        }
        __syncthreads();
    }

    float lsum = lacc0 + lacc1;
    lsum += __shfl_xor(lsum, 32);

    // combine key halves through LDS (kv buffer 0 is dead after the final barrier)
    // area per qg: 1024 floats oT + 64 floats lsum = 4352 B
    if (kh) {
        float* area = (float*)(smem + qg * 4352);
#pragma unroll
        for (int j = 0; j < 4; ++j)
            *(f32x4*)(area + j * 256 + lane * 4) =
                f32x4{oT[4 * j], oT[4 * j + 1], oT[4 * j + 2], oT[4 * j + 3]};
        area[1024 + lane] = lsum;
    }
    __syncthreads();
    if (!kh) {
        const float* area = (const float*)(smem + qg * 4352);
        lsum += area[1024 + lane];
        float inv = 1.0f / lsum;
        int b = bh >> 2, head = bh & 3;
        int n = q0 + q5;
        unsigned short* base = attnO + ((size_t)(b * NPOS + n)) * CHID + head * 32 + 4 * h;
#pragma unroll
        for (int j = 0; j < 4; ++j) {
            f32x4 r = *(const f32x4*)(area + j * 256 + lane * 4);
            unsigned long long d =
                (unsigned long long)pk2bf((oT[4 * j] + r[0]) * inv, (oT[4 * j + 1] + r[1]) * inv) |
                ((unsigned long long)pk2bf((oT[4 * j + 2] + r[2]) * inv, (oT[4 * j + 3] + r[3]) * inv) << 32);
            *(unsigned long long*)(base + 8 * j) = d;
        }
    }
}

// ---------------- kernel 4: output projection GEMM + bias, LDS-staged ----------------
__global__ __launch_bounds__(256, 4) void k_out(const unsigned short* __restrict__ wo,
                                                const unsigned short* __restrict__ attnO,
                                                const float* __restrict__ bias,
                                                float* __restrict__ out) {
    __shared__ __align__(16) unsigned char smem[2 * 12288];   // 24 KB
    int mt = blockIdx.x & 1;
    int nt = blockIdx.x >> 1;
    int wid = threadIdx.x >> 6, lane = threadIdx.x & 63;
    int quad = lane >> 4, low4 = lane & 15;
    int o0 = mt * 128, n0 = nt * 64;
    int lb = lane * 16;

    const unsigned short* srcA0 = wo + (size_t)(o0 + wid * 32 + low4) * CHID + quad * 8;
    const unsigned short* srcA1 = srcA0 + 16 * CHID;
    const unsigned short* srcB  = attnO + (size_t)(n0 + wid * 16 + low4) * CHID + quad * 8;
    int dA0 = wid * 2048, dA1 = dA0 + 1024, dB = 8192 + wid * 1024;

    async_cp16(srcA0, smem + dA0 + lb);
    async_cp16(srcA1, smem + dA1 + lb);
    async_cp16(srcB,  smem + dB  + lb);
    __syncthreads();

    f32x4 acc[2][4] = {};
    for (int c = 0; c < 4; ++c) {
        if (c < 3) {
            unsigned char* nxt = smem + ((c + 1) & 1) * 12288;
            async_cp16(srcA0 + (c + 1) * 32, nxt + dA0 + lb);
            async_cp16(srcA1 + (c + 1) * 32, nxt + dA1 + lb);
            async_cp16(srcB  + (c + 1) * 32, nxt + dB  + lb);
        }
        const unsigned char* cur = smem + (c & 1) * 12288;
        s16x8 a0 = *(const s16x8*)(cur + wid * 2048 + lb);
        s16x8 a1 = *(const s16x8*)(cur + wid * 2048 + 1024 + lb);
#pragma unroll
        for (int j = 0; j < 4; ++j) {
            s16x8 bj = *(const s16x8*)(cur + 8192 + j * 1024 + lb);
            acc[0][j] = __builtin_amdgcn_mfma_f32_16x16x32_bf16(a0, bj, acc[0][j], 0, 0, 0);
            acc[1][j] = __builtin_amdgcn_mfma_f32_16x16x32_bf16(a1, bj, acc[1][j], 0, 0, 0);
        }
        __syncthreads();
    }

#pragma unroll
    for (int i = 0; i < 2; ++i) {
        int ob = o0 + wid * 32 + i * 16 + quad * 4;
#pragma unroll
        for (int j = 0; j < 4; ++j) {
            int nG = n0 + j * 16 + low4;
            int b = nG >> 12, n = nG & 4095;
#pragma unroll
            for (int r = 0; r < 4; ++r) {
                int o = ob + r;
                out[((size_t)(b * CIN + o)) * NPOS + n] = acc[i][j][r] + bias[o];
            }
        }
    }
}

extern "C" void kernel_launch(void* const* d_in, const int* in_sizes, int n_in,
                              void* d_out, int out_size, void* d_ws, size_t ws_size,
                              hipStream_t stream) {
    const float* x    = (const float*)d_in[0];
    const float* wqkv = (const float*)d_in[1];
    const float* wout = (const float*)d_in[2];
    const float* bout = (const float*)d_in[3];
    float* out = (float*)d_out;

    unsigned short* Q       = (unsigned short*)d_ws;
    unsigned short* K       = Q + (size_t)BH * NPOS * 32;       // +4 MB
    unsigned short* V       = K + (size_t)BH * NPOS * 32;       // +4 MB
    unsigned short* attnO   = V + (size_t)BH * 32 * NPOS;       // +4 MB
    unsigned short* xT      = attnO + (size_t)NTOT * CHID;      // +4 MB
    unsigned short* wqkv_bf = xT + (size_t)NTOT * CIN;          // +8 MB
    unsigned short* wout_bf = wqkv_bf + QKV_O * CIN;            // +192 KB

    k_prep<<<TBLOCKS + (QKV_O * CIN + 255) / 256, 256, 0, stream>>>(x, xT, wqkv, wout, wqkv_bf, wout_bf);
    k_qkv<<<3 * (NTOT / 64), 256, 0, stream>>>(wqkv_bf, xT, Q, K, V);
    k_attn<<<(NPOS / 64) * BH, 256, 0, stream>>>(Q, K, V, attnO);
    k_out<<<2 * (NTOT / 64), 256, 0, stream>>>(wout_bf, attnO, bout, out);
}